// Round 17
// baseline (39.829 us; speedup 1.0000x reference)
//
#include <hip/hip_runtime.h>
#include <hip/hip_bf16.h>
#include <math.h>

#define BB 8
#define NN 2048
#define CC 128
#define DD 128

typedef __attribute__((ext_vector_type(8))) short short8;
typedef __attribute__((ext_vector_type(4))) float f32x4;

static __device__ __forceinline__ unsigned short f2bf(float f) {
    __hip_bfloat16 h = __float2bfloat16(f);
    return *reinterpret_cast<unsigned short*>(&h);
}
static __device__ __forceinline__ float bf2f(unsigned short u) {
    __hip_bfloat16 h = *reinterpret_cast<__hip_bfloat16*>(&u);
    return __bfloat162float(h);
}

// ---------------- Kernel A: fused adj-pack (blocks 0..255) + Wh compute (256..511).
#define PACKB 256
__global__ __launch_bounds__(256) void prep_wh_kernel(
    const int* __restrict__ adj, unsigned int* __restrict__ padj,
    const float* __restrict__ x, const float* __restrict__ W,
    const float* __restrict__ a,
    unsigned short* __restrict__ WhbT,
    float* __restrict__ f1, float* __restrict__ E2g, float* __restrict__ G2g)
{
    __shared__ unsigned short Whs[128 * 136];
    __shared__ unsigned short Wls[128 * 136];
    const int bx  = blockIdx.x;
    const int tid = threadIdx.x;

    if (bx < PACKB) {
        const int wid = bx * 256 + tid;
        #pragma unroll
        for (int rep = 0; rep < 2; ++rep) {
            const int word = wid + rep * 65536;
            const int4* src = (const int4*)adj + (size_t)word * 8;
            unsigned int m = 0;
            #pragma unroll
            for (int k = 0; k < 8; ++k) {
                int4 v = src[k];
                m |= (v.x > 0 ? 1u : 0u) << (k * 4);
                m |= (v.y > 0 ? 1u : 0u) << (k * 4 + 1);
                m |= (v.z > 0 ? 1u : 0u) << (k * 4 + 2);
                m |= (v.w > 0 ? 1u : 0u) << (k * 4 + 3);
            }
            padj[word] = m;
        }
        return;
    }

    const int g  = bx - PACKB;
    const int b  = g & 7;            // XCD-locality: batch b -> XCD b
    const int n0 = (g >> 3) * 64;

    #pragma unroll
    for (int k = 0; k < 16; ++k) {
        const int e   = tid + 256 * k;
        float4 wv = *(const float4*)&W[e * 4];
        const int row = e >> 5;
        const int col = (e & 31) * 4;
        ushort4 hv, lv;
        hv.x = f2bf(wv.x); lv.x = f2bf(wv.x - bf2f(hv.x));
        hv.y = f2bf(wv.y); lv.y = f2bf(wv.y - bf2f(hv.y));
        hv.z = f2bf(wv.z); lv.z = f2bf(wv.z - bf2f(hv.z));
        hv.w = f2bf(wv.w); lv.w = f2bf(wv.w - bf2f(hv.w));
        *(ushort4*)&Whs[row * 136 + col] = hv;
        *(ushort4*)&Wls[row * 136 + col] = lv;
    }
    __syncthreads();

    const int w    = tid >> 6;
    const int lane = tid & 63;
    const int fr   = lane & 15, fk = lane >> 4;
    const int n    = n0 + w * 16 + fr;

    short8 bh[4], bl[4];
    const float* xrow = &x[((size_t)(b * NN) + n) * CC];
    #pragma unroll
    for (int ks = 0; ks < 4; ++ks) {
        float xv[8];
        *(float4*)&xv[0] = *(const float4*)&xrow[(ks * 4 + fk) * 8];
        *(float4*)&xv[4] = *(const float4*)&xrow[(ks * 4 + fk) * 8 + 4];
        #pragma unroll
        for (int e = 0; e < 8; ++e) {
            unsigned short h = f2bf(xv[e]);
            bh[ks][e] = (short)h;
            bl[ks][e] = (short)f2bf(xv[e] - bf2f(h));
        }
    }

    f32x4 acc[8];
    #pragma unroll
    for (int dt = 0; dt < 8; ++dt) acc[dt] = (f32x4){0.f, 0.f, 0.f, 0.f};

    #pragma unroll
    for (int dt = 0; dt < 8; ++dt) {
        #pragma unroll
        for (int ks = 0; ks < 4; ++ks) {
            const int off = (dt * 16 + fr) * 136 + (ks * 4 + fk) * 8;
            short8 aH = *(const short8*)&Whs[off];
            short8 aL = *(const short8*)&Wls[off];
            acc[dt] = __builtin_amdgcn_mfma_f32_16x16x32_bf16(aH, bh[ks], acc[dt], 0, 0, 0);
            acc[dt] = __builtin_amdgcn_mfma_f32_16x16x32_bf16(aH, bl[ks], acc[dt], 0, 0, 0);
            acc[dt] = __builtin_amdgcn_mfma_f32_16x16x32_bf16(aL, bh[ks], acc[dt], 0, 0, 0);
        }
    }

    float p1 = 0.f, p2 = 0.f;
    #pragma unroll
    for (int dt = 0; dt < 8; ++dt) {
        #pragma unroll
        for (int r = 0; r < 4; ++r) {
            const int d = dt * 16 + fk * 4 + r;
            p1 += acc[dt][r] * a[d];
            p2 += acc[dt][r] * a[DD + d];
        }
    }
    p1 += __shfl_xor(p1, 16); p1 += __shfl_xor(p1, 32);
    p2 += __shfl_xor(p2, 16); p2 += __shfl_xor(p2, 32);
    if (fk == 0) {
        f1[b * NN + n]  = p1;
        E2g[b * NN + n] = __expf(p2);
        G2g[b * NN + n] = __expf(0.2f * p2);
    }

    #pragma unroll
    for (int dt = 0; dt < 8; ++dt) {
        #pragma unroll
        for (int r = 0; r < 4; ++r) {
            const int d = dt * 16 + fk * 4 + r;
            WhbT[((size_t)(b * 128 + d)) * NN + n] = f2bf(acc[dt][r]);
        }
    }
}

// ---------------- Kernel C: single-pass MFMA attention. Block = 64 i x 128 d x ALL j.
// 8 waves split as (wr 2 x wc 2 x kh 2): wave tile 32i x 64d x its 32-j half of each
// 64-j chunk -> 6 LDS reads per 8 MFMA (was 8). kh-partner partial sums merged via T.
__global__ __launch_bounds__(512) void gat_kernel(
    const unsigned short* __restrict__ WhbT,   // [b][128 d][2048 n] bf16
    const unsigned int* __restrict__ padj,     // [2048][64] bitmask
    const float* __restrict__ f1,
    const float* __restrict__ E2g, const float* __restrict__ G2g,
    float* __restrict__ out)
{
    constexpr int NC = NN / 64;                 // 32 chunks
    // [Bs0 16K][Bs1 16K][Ps0 8K][Ps1 8K][E2s 8K][G2s 8K][Srow 256]
    __shared__ __align__(16) unsigned char smem[66048];
    unsigned short* Bs0 = (unsigned short*)smem;
    unsigned short* Bs1 = (unsigned short*)(smem + 16384);
    unsigned short* Ps0 = (unsigned short*)(smem + 32768);
    unsigned short* Ps1 = (unsigned short*)(smem + 40960);
    float* E2s  = (float*)(smem + 49152);
    float* G2s  = (float*)(smem + 57344);
    float* Srow = (float*)(smem + 65536);
    float* T    = (float*)smem;                 // 33.8 KB alias, used after final barrier

    const int tid  = threadIdx.x;
    const int gblk = blockIdx.x;
    const int b    = gblk & 7;                  // XCD-locality
    const int i0   = (gblk >> 3) * 64;

    #pragma unroll
    for (int k = 0; k < NN / 512; ++k) {
        E2s[tid + 512 * k] = E2g[b * NN + tid + 512 * k];
        G2s[tid + 512 * k] = G2g[b * NN + tid + 512 * k];
    }

    // P role
    const int prow = tid >> 3;
    const int pjb  = tid & 7;
    const float f1r = f1[b * NN + i0 + prow];
    const float E1r = __expf(f1r);
    const float G1r = __expf(0.2f * f1r);
    const int psw = ((pjb ^ (prow & 7)) << 3);
    const unsigned int* padjRow = padj + (size_t)(i0 + prow) * 64;

    // MFMA role: wave (wr, wc, kh)
    const int w    = tid >> 6;
    const int wr   = w >> 2;
    const int wc   = (w >> 1) & 1;
    const int kh   = w & 1;
    const int lane = tid & 63;
    const int fr   = lane & 15;
    const int fk   = lane >> 4;
    const int sbK  = (((kh * 4 + fk) ^ (fr & 7)) << 3);   // this wave's j-slot swizzle
    f32x4 acc0[4], acc1[4];
    #pragma unroll
    for (int dt = 0; dt < 4; ++dt) {
        acc0[dt] = (f32x4){0.f,0.f,0.f,0.f};
        acc1[dt] = (f32x4){0.f,0.f,0.f,0.f};
    }
    float s_part = 0.f;

    // B staging (R13-proven): 1024 x 16B loads, 2 per thread, XOR-swizzled slots
    const size_t wbase = (size_t)b * 128 * NN;
    const int g0 = tid,       gd0 = g0 >> 3, gj0 = (g0 & 7) * 8;
    const int g1 = tid + 512, gd1 = g1 >> 3, gj1 = (g1 & 7) * 8;
    const int sw0 = gd0 * 64 + ((((g0) & 7) ^ (gd0 & 7)) << 3);
    const int sw1 = gd1 * 64 + ((((g1) & 7) ^ (gd1 & 7)) << 3);

    uint4 brA0, brA1, brB0, brB1;
    unsigned int pwA, pwB;

#define LOADSET(s, c) do {                                                   \
        br##s##0 = *(const uint4*)&WhbT[wbase + (size_t)gd0 * NN + (c) * 64 + gj0]; \
        br##s##1 = *(const uint4*)&WhbT[wbase + (size_t)gd1 * NN + (c) * 64 + gj1]; \
        pw##s    = padjRow[(c) * 2 + (pjb >> 2)];                            \
    } while (0)

#define PSTAGE(Bsb, Psb, s, c) do {                                          \
        float4 eA = *(const float4*)&E2s[(c) * 64 + pjb * 8];                \
        float4 eB = *(const float4*)&E2s[(c) * 64 + pjb * 8 + 4];            \
        float4 gA = *(const float4*)&G2s[(c) * 64 + pjb * 8];                \
        float4 gB = *(const float4*)&G2s[(c) * 64 + pjb * 8 + 4];            \
        float ev[8], gv[8];                                                  \
        *(float4*)&ev[0] = eA; *(float4*)&ev[4] = eB;                        \
        *(float4*)&gv[0] = gA; *(float4*)&gv[4] = gB;                        \
        unsigned int pbits = (pw##s >> ((pjb & 3) << 3)) & 0xffu;            \
        unsigned short pks[8];                                               \
        float ssum = 0.f;                                                    \
        _Pragma("unroll")                                                    \
        for (int e = 0; e < 8; ++e) {                                        \
            float mv = E1r * ev[e];                                          \
            float gg = G1r * gv[e];                                          \
            float wv = fmaxf(mv, gg);                                        \
            wv = ((pbits >> e) & 1u) ? wv : 0.f;                             \
            unsigned short bw = f2bf(wv);                                    \
            pks[e] = bw;                                                     \
            ssum += bf2f(bw);                                                \
        }                                                                    \
        s_part += ssum;                                                      \
        *(uint4*)&Bsb[sw0] = br##s##0;                                       \
        *(uint4*)&Bsb[sw1] = br##s##1;                                       \
        uint4 pv;                                                            \
        pv.x = (unsigned int)pks[0] | ((unsigned int)pks[1] << 16);          \
        pv.y = (unsigned int)pks[2] | ((unsigned int)pks[3] << 16);          \
        pv.z = (unsigned int)pks[4] | ((unsigned int)pks[5] << 16);          \
        pv.w = (unsigned int)pks[6] | ((unsigned int)pks[7] << 16);          \
        *(uint4*)&Psb[prow * 64 + psw] = pv;                                 \
    } while (0)

#define MFMAC(Bsb, Psb) do {                                                 \
        __builtin_amdgcn_s_setprio(1);                                       \
        short8 aF0 = *(const short8*)&Psb[(wr * 32 + fr) * 64 + sbK];        \
        short8 aF1 = *(const short8*)&Psb[(wr * 32 + 16 + fr) * 64 + sbK];   \
        short8 bF0 = *(const short8*)&Bsb[(wc * 64 +      fr) * 64 + sbK];   \
        short8 bF1 = *(const short8*)&Bsb[(wc * 64 + 16 + fr) * 64 + sbK];   \
        short8 bF2 = *(const short8*)&Bsb[(wc * 64 + 32 + fr) * 64 + sbK];   \
        short8 bF3 = *(const short8*)&Bsb[(wc * 64 + 48 + fr) * 64 + sbK];   \
        acc0[0] = __builtin_amdgcn_mfma_f32_16x16x32_bf16(aF0, bF0, acc0[0], 0, 0, 0); \
        acc0[1] = __builtin_amdgcn_mfma_f32_16x16x32_bf16(aF0, bF1, acc0[1], 0, 0, 0); \
        acc0[2] = __builtin_amdgcn_mfma_f32_16x16x32_bf16(aF0, bF2, acc0[2], 0, 0, 0); \
        acc0[3] = __builtin_amdgcn_mfma_f32_16x16x32_bf16(aF0, bF3, acc0[3], 0, 0, 0); \
        acc1[0] = __builtin_amdgcn_mfma_f32_16x16x32_bf16(aF1, bF0, acc1[0], 0, 0, 0); \
        acc1[1] = __builtin_amdgcn_mfma_f32_16x16x32_bf16(aF1, bF1, acc1[1], 0, 0, 0); \
        acc1[2] = __builtin_amdgcn_mfma_f32_16x16x32_bf16(aF1, bF2, acc1[2], 0, 0, 0); \
        acc1[3] = __builtin_amdgcn_mfma_f32_16x16x32_bf16(aF1, bF3, acc1[3], 0, 0, 0); \
        __builtin_amdgcn_s_setprio(0);                                       \
    } while (0)

    // prologue: chunk0 -> buf0; prefetch chunk1
    LOADSET(A, 0);
    __syncthreads();                 // E2s/G2s ready
    PSTAGE(Bs0, Ps0, A, 0);
    LOADSET(B, 1);
    __syncthreads();                 // buf0 ready

    #pragma unroll 1
    for (int cc = 0; cc < NC; cc += 2) {
        PSTAGE(Bs1, Ps1, B, cc + 1);
        if (cc + 2 < NC) LOADSET(A, cc + 2);
        MFMAC(Bs0, Ps0);
        __syncthreads();
        if (cc + 2 < NC) PSTAGE(Bs0, Ps0, A, cc + 2);
        if (cc + 3 < NC) LOADSET(B, cc + 3);
        MFMAC(Bs1, Ps1);
        __syncthreads();
    }

#undef LOADSET
#undef PSTAGE
#undef MFMAC

    // row-sum: 8 threads per row (numerator-consistent bf16-rounded sums)
    {
        float v = s_part;
        v += __shfl_xor(v, 1); v += __shfl_xor(v, 2); v += __shfl_xor(v, 4);
        if (pjb == 0) Srow[prow] = v;
    }

    // kh=1 waves deposit raw partial acc into T (aliases dead tile buffers)
    if (kh) {
        #pragma unroll
        for (int it = 0; it < 2; ++it) {
            #pragma unroll
            for (int dt = 0; dt < 4; ++dt) {
                f32x4 av = it ? acc1[dt] : acc0[dt];
                #pragma unroll
                for (int r = 0; r < 4; ++r) {
                    const int i = wr * 32 + it * 16 + fk * 4 + r;
                    const int d = wc * 64 + dt * 16 + fr;
                    T[i * 132 + d] = av[r];
                }
            }
        }
    }
    __syncthreads();

    // kh=0 waves: merge partner partials, normalize, elu
    if (!kh) {
        #pragma unroll
        for (int it = 0; it < 2; ++it) {
            #pragma unroll
            for (int dt = 0; dt < 4; ++dt) {
                f32x4 av = it ? acc1[dt] : acc0[dt];
                #pragma unroll
                for (int r = 0; r < 4; ++r) {
                    const int i = wr * 32 + it * 16 + fk * 4 + r;
                    const int d = wc * 64 + dt * 16 + fr;
                    float hv = (av[r] + T[i * 132 + d]) / Srow[i];
                    hv = (hv > 0.f) ? hv : expm1f(hv);
                    T[i * 132 + d] = hv;
                }
            }
        }
    }
    __syncthreads();

    #pragma unroll
    for (int k = 0; k < 4; ++k) {
        const int g   = tid + 512 * k;     // 2048 float4 = 64 x 128
        const int row = g >> 5;
        const int d4  = (g & 31) * 4;
        float4 h = *(const float4*)&T[row * 132 + d4];
        *(float4*)&out[((size_t)(b * NN) + i0 + row) * DD + d4] = h;
    }
}

extern "C" void kernel_launch(void* const* d_in, const int* in_sizes, int n_in,
                              void* d_out, int out_size, void* d_ws, size_t ws_size,
                              hipStream_t stream) {
    const float* x   = (const float*)d_in[0];
    const int*   adj = (const int*)d_in[1];
    const float* W   = (const float*)d_in[2];
    const float* a   = (const float*)d_in[3];
    float* out = (float*)d_out;

    char* p = (char*)d_ws;
    unsigned short* WhbT = (unsigned short*)p; p += (size_t)BB * NN * DD * 2;  // 4 MB
    float* f1  = (float*)p; p += (size_t)BB * NN * 4;                          // 64 KB
    float* E2g = (float*)p; p += (size_t)BB * NN * 4;                          // 64 KB
    float* G2g = (float*)p; p += (size_t)BB * NN * 4;                          // 64 KB
    unsigned int* padj = (unsigned int*)p;    p += (size_t)NN * 64 * 4;        // 512 KB

    prep_wh_kernel<<<PACKB + (NN / 64) * BB, 256, 0, stream>>>(
        adj, padj, x, W, a, WhbT, f1, E2g, G2g);
    gat_kernel<<<(NN / 64) * BB, 512, 0, stream>>>(
        WhbT, padj, f1, E2g, G2g, out);
}

// Round 18
// 39.697 us; speedup vs baseline: 1.0033x; 1.0033x over previous
//
#include <hip/hip_runtime.h>
#include <hip/hip_bf16.h>
#include <math.h>

#define BB 8
#define NN 2048
#define CC 128
#define DD 128

typedef __attribute__((ext_vector_type(8))) short short8;
typedef __attribute__((ext_vector_type(4))) float f32x4;

static __device__ __forceinline__ unsigned short f2bf(float f) {
    __hip_bfloat16 h = __float2bfloat16(f);
    return *reinterpret_cast<unsigned short*>(&h);
}
static __device__ __forceinline__ float bf2f(unsigned short u) {
    __hip_bfloat16 h = *reinterpret_cast<__hip_bfloat16*>(&u);
    return __bfloat162float(h);
}
static __device__ __forceinline__ void gload_lds16(const void* g, void* l) {
    __builtin_amdgcn_global_load_lds(
        (const __attribute__((address_space(1))) unsigned int*)g,
        (__attribute__((address_space(3))) unsigned int*)l, 16, 0, 0);
}

// ---------------- Kernel A: fused adj-pack (blocks 0..255) + Wh compute (256..511).
// WhbTs layout: [b][chunk c][8192 ushort image]; slot (D,JB,e) = Wh[D][c*64+((JB^(D&7))*8+e)]
// so gat's global_load_lds produces the XOR-swizzled LDS image directly (m173 pattern).
#define PACKB 256
__global__ __launch_bounds__(256) void prep_wh_kernel(
    const int* __restrict__ adj, unsigned int* __restrict__ padj,
    const float* __restrict__ x, const float* __restrict__ W,
    const float* __restrict__ a,
    unsigned short* __restrict__ WhbTs,
    float* __restrict__ f1, float* __restrict__ E2g, float* __restrict__ G2g)
{
    __shared__ unsigned short Whs[128 * 136];
    __shared__ unsigned short Wls[128 * 136];
    const int bx  = blockIdx.x;
    const int tid = threadIdx.x;

    if (bx < PACKB) {
        const int wid = bx * 256 + tid;
        #pragma unroll
        for (int rep = 0; rep < 2; ++rep) {
            const int word = wid + rep * 65536;
            const int4* src = (const int4*)adj + (size_t)word * 8;
            unsigned int m = 0;
            #pragma unroll
            for (int k = 0; k < 8; ++k) {
                int4 v = src[k];
                m |= (v.x > 0 ? 1u : 0u) << (k * 4);
                m |= (v.y > 0 ? 1u : 0u) << (k * 4 + 1);
                m |= (v.z > 0 ? 1u : 0u) << (k * 4 + 2);
                m |= (v.w > 0 ? 1u : 0u) << (k * 4 + 3);
            }
            padj[word] = m;
        }
        return;
    }

    const int g  = bx - PACKB;
    const int b  = g & 7;            // XCD-locality: batch b -> XCD b
    const int n0 = (g >> 3) * 64;

    #pragma unroll
    for (int k = 0; k < 16; ++k) {
        const int e   = tid + 256 * k;
        float4 wv = *(const float4*)&W[e * 4];
        const int row = e >> 5;
        const int col = (e & 31) * 4;
        ushort4 hv, lv;
        hv.x = f2bf(wv.x); lv.x = f2bf(wv.x - bf2f(hv.x));
        hv.y = f2bf(wv.y); lv.y = f2bf(wv.y - bf2f(hv.y));
        hv.z = f2bf(wv.z); lv.z = f2bf(wv.z - bf2f(hv.z));
        hv.w = f2bf(wv.w); lv.w = f2bf(wv.w - bf2f(hv.w));
        *(ushort4*)&Whs[row * 136 + col] = hv;
        *(ushort4*)&Wls[row * 136 + col] = lv;
    }
    __syncthreads();

    const int w    = tid >> 6;
    const int lane = tid & 63;
    const int fr   = lane & 15, fk = lane >> 4;
    const int n    = n0 + w * 16 + fr;

    short8 bh[4], bl[4];
    const float* xrow = &x[((size_t)(b * NN) + n) * CC];
    #pragma unroll
    for (int ks = 0; ks < 4; ++ks) {
        float xv[8];
        *(float4*)&xv[0] = *(const float4*)&xrow[(ks * 4 + fk) * 8];
        *(float4*)&xv[4] = *(const float4*)&xrow[(ks * 4 + fk) * 8 + 4];
        #pragma unroll
        for (int e = 0; e < 8; ++e) {
            unsigned short h = f2bf(xv[e]);
            bh[ks][e] = (short)h;
            bl[ks][e] = (short)f2bf(xv[e] - bf2f(h));
        }
    }

    f32x4 acc[8];
    #pragma unroll
    for (int dt = 0; dt < 8; ++dt) acc[dt] = (f32x4){0.f, 0.f, 0.f, 0.f};

    #pragma unroll
    for (int dt = 0; dt < 8; ++dt) {
        #pragma unroll
        for (int ks = 0; ks < 4; ++ks) {
            const int off = (dt * 16 + fr) * 136 + (ks * 4 + fk) * 8;
            short8 aH = *(const short8*)&Whs[off];
            short8 aL = *(const short8*)&Wls[off];
            acc[dt] = __builtin_amdgcn_mfma_f32_16x16x32_bf16(aH, bh[ks], acc[dt], 0, 0, 0);
            acc[dt] = __builtin_amdgcn_mfma_f32_16x16x32_bf16(aH, bl[ks], acc[dt], 0, 0, 0);
            acc[dt] = __builtin_amdgcn_mfma_f32_16x16x32_bf16(aL, bh[ks], acc[dt], 0, 0, 0);
        }
    }

    float p1 = 0.f, p2 = 0.f;
    #pragma unroll
    for (int dt = 0; dt < 8; ++dt) {
        #pragma unroll
        for (int r = 0; r < 4; ++r) {
            const int d = dt * 16 + fk * 4 + r;
            p1 += acc[dt][r] * a[d];
            p2 += acc[dt][r] * a[DD + d];
        }
    }
    p1 += __shfl_xor(p1, 16); p1 += __shfl_xor(p1, 32);
    p2 += __shfl_xor(p2, 16); p2 += __shfl_xor(p2, 32);
    if (fk == 0) {
        f1[b * NN + n]  = p1;
        E2g[b * NN + n] = __expf(p2);
        G2g[b * NN + n] = __expf(0.2f * p2);
    }

    // swizzled-image store: thread-constant (c, jb, e); d varies
    {
        const int c  = n >> 6;
        const int jb = (n >> 3) & 7;
        const int e  = n & 7;
        unsigned short* dst = WhbTs + ((size_t)(b * 32 + c) << 13) + e;
        #pragma unroll
        for (int dt = 0; dt < 8; ++dt) {
            #pragma unroll
            for (int r = 0; r < 4; ++r) {
                const int d = dt * 16 + fk * 4 + r;
                dst[d * 64 + ((jb ^ (d & 7)) << 3)] = f2bf(acc[dt][r]);
            }
        }
    }
}

// ---------------- Kernel C: single-pass MFMA attention. Block = 32 i x 128 d x ALL j.
// B staged via global_load_lds DMA from the pre-swizzled WhbTs image (no VGPR round
// trip, no LDS stage-write instrs). P via VALU + ds_write (dbuf). 1 barrier/chunk.
__global__ __launch_bounds__(256) void gat_kernel(
    const unsigned short* __restrict__ WhbTs,  // [b][32 c][8192] swizzled image
    const unsigned int* __restrict__ padj,     // [2048][64] bitmask
    const float* __restrict__ f1,
    const float* __restrict__ E2g, const float* __restrict__ G2g,
    float* __restrict__ out)
{
    constexpr int NC = NN / 64;                 // 32 chunks
    // [Bs0 16K][Bs1 16K][Ps0 4K][Ps1 4K][E2s 8K][G2s 8K][Srow 128][Sred 128] = 57.6 KB
    __shared__ __align__(16) unsigned char smem[57600];
    unsigned short* Bs0 = (unsigned short*)smem;
    unsigned short* Bs1 = (unsigned short*)(smem + 16384);
    unsigned short* Ps0 = (unsigned short*)(smem + 32768);
    unsigned short* Ps1 = (unsigned short*)(smem + 36864);
    float* E2s  = (float*)(smem + 40960);
    float* G2s  = (float*)(smem + 49152);
    float* Srow = (float*)(smem + 57344);
    float* Sred = (float*)(smem + 57472);
    float* T    = (float*)smem;                 // aliases tiles after final barrier

    const int tid  = threadIdx.x;
    const int gblk = blockIdx.x;
    const int b    = gblk & 7;                  // XCD-locality
    const int i0   = (gblk >> 3) * 32;

    #pragma unroll
    for (int k = 0; k < NN / 256; ++k) {
        E2s[tid + 256 * k] = E2g[b * NN + tid + 256 * k];
        G2s[tid + 256 * k] = G2g[b * NN + tid + 256 * k];
    }

    // P role: row = tid>>3 (32 rows), 8 j-elems at pjb*8
    const int prow = tid >> 3;
    const int pjb  = tid & 7;
    const float f1r = f1[b * NN + i0 + prow];
    const float E1r = __expf(f1r);
    const float G1r = __expf(0.2f * f1r);
    const int psw = ((pjb ^ (prow & 7)) << 3);
    const unsigned int* padjRow = padj + (size_t)(i0 + prow) * 64;

    // MFMA role: wave w covers d-cols w*32..w*32+31, i-rows 0..31
    const int w    = tid >> 6;
    const int lane = tid & 63;
    const int fr   = lane & 15;
    const int fk   = lane >> 4;
    f32x4 acc00 = {0.f,0.f,0.f,0.f}, acc01 = {0.f,0.f,0.f,0.f};
    f32x4 acc10 = {0.f,0.f,0.f,0.f}, acc11 = {0.f,0.f,0.f,0.f};
    float s_part = 0.f;

    // DMA staging bases: wave w stages bytes [w*4096, w*4096+4096) of each 16 KB chunk
    const char* gch = (const char*)(WhbTs + ((size_t)(b * 32) << 13)) + (w << 12) + lane * 16;
    unsigned int pwA, pwB;

#define BSTAGE(BsDst, c) do {                                                \
        const char* gsrc = gch + ((size_t)(c) << 14);                        \
        char* ldst = (char*)(BsDst) + (w << 12);                             \
        gload_lds16(gsrc,        ldst);                                      \
        gload_lds16(gsrc + 1024, ldst + 1024);                               \
        gload_lds16(gsrc + 2048, ldst + 2048);                               \
        gload_lds16(gsrc + 3072, ldst + 3072);                               \
    } while (0)

#define PSTAGE(Psb, s, c) do {                                               \
        float4 eA = *(const float4*)&E2s[(c) * 64 + pjb * 8];                \
        float4 eB = *(const float4*)&E2s[(c) * 64 + pjb * 8 + 4];            \
        float4 gA = *(const float4*)&G2s[(c) * 64 + pjb * 8];                \
        float4 gB = *(const float4*)&G2s[(c) * 64 + pjb * 8 + 4];            \
        float ev[8], gv[8];                                                  \
        *(float4*)&ev[0] = eA; *(float4*)&ev[4] = eB;                        \
        *(float4*)&gv[0] = gA; *(float4*)&gv[4] = gB;                        \
        unsigned int pbits = (pw##s >> ((pjb & 3) << 3)) & 0xffu;            \
        unsigned short pks[8];                                               \
        float ssum = 0.f;                                                    \
        _Pragma("unroll")                                                    \
        for (int e = 0; e < 8; ++e) {                                        \
            float mv = E1r * ev[e];                                          \
            float gg = G1r * gv[e];                                          \
            float wv = fmaxf(mv, gg);                                        \
            wv = ((pbits >> e) & 1u) ? wv : 0.f;                             \
            unsigned short bw = f2bf(wv);                                    \
            pks[e] = bw;                                                     \
            ssum += bf2f(bw);                                                \
        }                                                                    \
        s_part += ssum;                                                      \
        uint4 pv;                                                            \
        pv.x = (unsigned int)pks[0] | ((unsigned int)pks[1] << 16);          \
        pv.y = (unsigned int)pks[2] | ((unsigned int)pks[3] << 16);          \
        pv.z = (unsigned int)pks[4] | ((unsigned int)pks[5] << 16);          \
        pv.w = (unsigned int)pks[6] | ((unsigned int)pks[7] << 16);          \
        *(uint4*)&Psb[prow * 64 + psw] = pv;                                 \
    } while (0)

#define MFMAC(Bsb, Psb) do {                                                 \
        __builtin_amdgcn_s_setprio(1);                                       \
        _Pragma("unroll")                                                    \
        for (int ks = 0; ks < 2; ++ks) {                                     \
            const int jbl = ks * 4 + fk;                                     \
            const int sb  = ((jbl ^ (fr & 7)) << 3);                         \
            short8 aF0 = *(const short8*)&Psb[fr * 64 + sb];                 \
            short8 aF1 = *(const short8*)&Psb[(16 + fr) * 64 + sb];          \
            short8 bF0 = *(const short8*)&Bsb[(w * 32 + fr) * 64 + sb];      \
            short8 bF1 = *(const short8*)&Bsb[(w * 32 + 16 + fr) * 64 + sb]; \
            acc00 = __builtin_amdgcn_mfma_f32_16x16x32_bf16(aF0, bF0, acc00, 0, 0, 0); \
            acc01 = __builtin_amdgcn_mfma_f32_16x16x32_bf16(aF0, bF1, acc01, 0, 0, 0); \
            acc10 = __builtin_amdgcn_mfma_f32_16x16x32_bf16(aF1, bF0, acc10, 0, 0, 0); \
            acc11 = __builtin_amdgcn_mfma_f32_16x16x32_bf16(aF1, bF1, acc11, 0, 0, 0); \
        }                                                                    \
        __builtin_amdgcn_s_setprio(0);                                       \
    } while (0)

    // prologue: DMA chunk0 -> Bs0; EG staged; barrier drains both
    BSTAGE(Bs0, 0);
    pwA = padjRow[(pjb >> 2)];
    __syncthreads();                 // Bs0 + E2s/G2s ready
    BSTAGE(Bs1, 1);                  // DMA chunk1 in flight
    PSTAGE(Ps0, A, 0);
    pwB = padjRow[2 + (pjb >> 2)];
    __syncthreads();                 // Ps0 ready (Bs1 also drained, early but fine)

    #pragma unroll 1
    for (int cc = 0; cc < NC; cc += 2) {
        // phase A: compute chunk cc (Bs0/Ps0); prep P(cc+1)
        PSTAGE(Ps1, B, cc + 1);
        if (cc + 2 < NC) pwA = padjRow[(cc + 2) * 2 + (pjb >> 2)];
        MFMAC(Bs0, Ps0);
        __syncthreads();             // drains Ps1 writes (+ any DMA); Bs0 dead
        if (cc + 2 < NC) BSTAGE(Bs0, cc + 2);   // DMA into freed buffer
        // phase B: compute chunk cc+1 (Bs1/Ps1); prep P(cc+2)
        if (cc + 2 < NC) PSTAGE(Ps0, A, cc + 2);
        if (cc + 3 < NC) pwB = padjRow[(cc + 3) * 2 + (pjb >> 2)];
        MFMAC(Bs1, Ps1);
        __syncthreads();             // drains Bs0-DMA + Ps0; Bs1 dead
        if (cc + 3 < NC) BSTAGE(Bs1, cc + 3);
    }

#undef BSTAGE
#undef PSTAGE
#undef MFMAC

    // row-sum: 8 threads per row
    {
        float v = s_part;
        v += __shfl_xor(v, 1); v += __shfl_xor(v, 2); v += __shfl_xor(v, 4);
        if (pjb == 0) Srow[prow] = v;
    }
    __syncthreads();
    if (tid < 32) Sred[tid] = 1.0f / Srow[tid];
    __syncthreads();

    // normalize + elu into T (aliases tile buffers; all reads/DMA done)
    #pragma unroll
    for (int it = 0; it < 2; ++it) {
        #pragma unroll
        for (int dt = 0; dt < 2; ++dt) {
            f32x4 av = (it == 0) ? (dt == 0 ? acc00 : acc01)
                                 : (dt == 0 ? acc10 : acc11);
            #pragma unroll
            for (int r = 0; r < 4; ++r) {
                const int i = it * 16 + fk * 4 + r;
                const int d = w * 32 + dt * 16 + fr;
                float hv = av[r] * Sred[i];
                hv = (hv > 0.f) ? hv : expm1f(hv);
                T[i * 132 + d] = hv;
            }
        }
    }
    __syncthreads();

    #pragma unroll
    for (int k = 0; k < 4; ++k) {
        const int g   = tid + 256 * k;     // 1024 float4 = 32 x 128
        const int row = g >> 5;
        const int d4  = (g & 31) * 4;
        float4 h = *(const float4*)&T[row * 132 + d4];
        *(float4*)&out[((size_t)(b * NN) + i0 + row) * DD + d4] = h;
    }
}

extern "C" void kernel_launch(void* const* d_in, const int* in_sizes, int n_in,
                              void* d_out, int out_size, void* d_ws, size_t ws_size,
                              hipStream_t stream) {
    const float* x   = (const float*)d_in[0];
    const int*   adj = (const int*)d_in[1];
    const float* W   = (const float*)d_in[2];
    const float* a   = (const float*)d_in[3];
    float* out = (float*)d_out;

    char* p = (char*)d_ws;
    unsigned short* WhbTs = (unsigned short*)p; p += (size_t)BB * NN * DD * 2;  // 4 MB
    float* f1  = (float*)p; p += (size_t)BB * NN * 4;                           // 64 KB
    float* E2g = (float*)p; p += (size_t)BB * NN * 4;                           // 64 KB
    float* G2g = (float*)p; p += (size_t)BB * NN * 4;                           // 64 KB
    unsigned int* padj = (unsigned int*)p;     p += (size_t)NN * 64 * 4;        // 512 KB

    prep_wh_kernel<<<PACKB + (NN / 64) * BB, 256, 0, stream>>>(
        adj, padj, x, W, a, WhbTs, f1, E2g, G2g);
    gat_kernel<<<(NN / 32) * BB, 256, 0, stream>>>(
        WhbTs, padj, f1, E2g, G2g, out);
}

// Round 20
// 35.114 us; speedup vs baseline: 1.1343x; 1.1305x over previous
//
#include <hip/hip_runtime.h>
#include <hip/hip_bf16.h>
#include <math.h>

#define BB 8
#define NN 2048
#define CC 128
#define DD 128

typedef __attribute__((ext_vector_type(8))) short short8;
typedef __attribute__((ext_vector_type(4))) float f32x4;

static __device__ __forceinline__ unsigned short f2bf(float f) {
    __hip_bfloat16 h = __float2bfloat16(f);
    return *reinterpret_cast<unsigned short*>(&h);
}
static __device__ __forceinline__ float bf2f(unsigned short u) {
    __hip_bfloat16 h = *reinterpret_cast<__hip_bfloat16*>(&u);
    return __bfloat162float(h);
}

// ---------------- Kernel A: fused adj-pack (blocks 0..255) + Wh compute (256..511).
#define PACKB 256
__global__ __launch_bounds__(256) void prep_wh_kernel(
    const int* __restrict__ adj, unsigned int* __restrict__ padj,
    const float* __restrict__ x, const float* __restrict__ W,
    const float* __restrict__ a,
    unsigned short* __restrict__ WhbT,
    float* __restrict__ f1, float* __restrict__ E2g, float* __restrict__ G2g)
{
    __shared__ unsigned short Whs[128 * 136];
    __shared__ unsigned short Wls[128 * 136];
    const int bx  = blockIdx.x;
    const int tid = threadIdx.x;

    if (bx < PACKB) {
        const int wid = bx * 256 + tid;
        #pragma unroll
        for (int rep = 0; rep < 2; ++rep) {
            const int word = wid + rep * 65536;
            const int4* src = (const int4*)adj + (size_t)word * 8;
            unsigned int m = 0;
            #pragma unroll
            for (int k = 0; k < 8; ++k) {
                int4 v = src[k];
                m |= (v.x > 0 ? 1u : 0u) << (k * 4);
                m |= (v.y > 0 ? 1u : 0u) << (k * 4 + 1);
                m |= (v.z > 0 ? 1u : 0u) << (k * 4 + 2);
                m |= (v.w > 0 ? 1u : 0u) << (k * 4 + 3);
            }
            padj[word] = m;
        }
        return;
    }

    const int g  = bx - PACKB;
    const int b  = g & 7;            // XCD-locality: batch b -> XCD b
    const int n0 = (g >> 3) * 64;

    #pragma unroll
    for (int k = 0; k < 16; ++k) {
        const int e   = tid + 256 * k;
        float4 wv = *(const float4*)&W[e * 4];
        const int row = e >> 5;
        const int col = (e & 31) * 4;
        ushort4 hv, lv;
        hv.x = f2bf(wv.x); lv.x = f2bf(wv.x - bf2f(hv.x));
        hv.y = f2bf(wv.y); lv.y = f2bf(wv.y - bf2f(hv.y));
        hv.z = f2bf(wv.z); lv.z = f2bf(wv.z - bf2f(hv.z));
        hv.w = f2bf(wv.w); lv.w = f2bf(wv.w - bf2f(hv.w));
        *(ushort4*)&Whs[row * 136 + col] = hv;
        *(ushort4*)&Wls[row * 136 + col] = lv;
    }
    __syncthreads();

    const int w    = tid >> 6;
    const int lane = tid & 63;
    const int fr   = lane & 15, fk = lane >> 4;
    const int n    = n0 + w * 16 + fr;

    short8 bh[4], bl[4];
    const float* xrow = &x[((size_t)(b * NN) + n) * CC];
    #pragma unroll
    for (int ks = 0; ks < 4; ++ks) {
        float xv[8];
        *(float4*)&xv[0] = *(const float4*)&xrow[(ks * 4 + fk) * 8];
        *(float4*)&xv[4] = *(const float4*)&xrow[(ks * 4 + fk) * 8 + 4];
        #pragma unroll
        for (int e = 0; e < 8; ++e) {
            unsigned short h = f2bf(xv[e]);
            bh[ks][e] = (short)h;
            bl[ks][e] = (short)f2bf(xv[e] - bf2f(h));
        }
    }

    f32x4 acc[8];
    #pragma unroll
    for (int dt = 0; dt < 8; ++dt) acc[dt] = (f32x4){0.f, 0.f, 0.f, 0.f};

    #pragma unroll
    for (int dt = 0; dt < 8; ++dt) {
        #pragma unroll
        for (int ks = 0; ks < 4; ++ks) {
            const int off = (dt * 16 + fr) * 136 + (ks * 4 + fk) * 8;
            short8 aH = *(const short8*)&Whs[off];
            short8 aL = *(const short8*)&Wls[off];
            acc[dt] = __builtin_amdgcn_mfma_f32_16x16x32_bf16(aH, bh[ks], acc[dt], 0, 0, 0);
            acc[dt] = __builtin_amdgcn_mfma_f32_16x16x32_bf16(aH, bl[ks], acc[dt], 0, 0, 0);
            acc[dt] = __builtin_amdgcn_mfma_f32_16x16x32_bf16(aL, bh[ks], acc[dt], 0, 0, 0);
        }
    }

    float p1 = 0.f, p2 = 0.f;
    #pragma unroll
    for (int dt = 0; dt < 8; ++dt) {
        #pragma unroll
        for (int r = 0; r < 4; ++r) {
            const int d = dt * 16 + fk * 4 + r;
            p1 += acc[dt][r] * a[d];
            p2 += acc[dt][r] * a[DD + d];
        }
    }
    p1 += __shfl_xor(p1, 16); p1 += __shfl_xor(p1, 32);
    p2 += __shfl_xor(p2, 16); p2 += __shfl_xor(p2, 32);
    if (fk == 0) {
        f1[b * NN + n]  = p1;
        E2g[b * NN + n] = __expf(p2);
        G2g[b * NN + n] = __expf(0.2f * p2);
    }

    #pragma unroll
    for (int dt = 0; dt < 8; ++dt) {
        #pragma unroll
        for (int r = 0; r < 4; ++r) {
            const int d = dt * 16 + fk * 4 + r;
            WhbT[((size_t)(b * 128 + d)) * NN + n] = f2bf(acc[dt][r]);
        }
    }
}

// ---------------- Kernel C: single-pass MFMA attention, 64 i x 128 d x ALL j.
// FAT 128-j chunks (two proven 64-j sub-tiles per phase) -> 18 barriers instead of
// 34. CORRECTED smem map (R19 bug: Ps half is 8 KB, not 4 KB — Ps1 clobbered E2s).
__global__ __launch_bounds__(512) void gat_kernel(
    const unsigned short* __restrict__ WhbT,   // [b][128 d][2048 n] bf16
    const unsigned int* __restrict__ padj,     // [2048][64] bitmask
    const float* __restrict__ f1,
    const float* __restrict__ E2g, const float* __restrict__ G2g,
    float* __restrict__ out)
{
    constexpr int NF = NN / 128;                // 16 fat chunks
    // byte map: [Bs0 32K @0][Bs1 32K @32768][Ps0 16K @65536][Ps1 16K @81920]
    //           [E2s 8K @98304][G2s 8K @106496][Srow 256 @114688][Sred 256 @114944]
    __shared__ __align__(16) unsigned char smem[115200];
    unsigned short* Bs0 = (unsigned short*)smem;                 // 2 halves x 16 KB
    unsigned short* Bs1 = (unsigned short*)(smem + 32768);
    unsigned short* Ps0 = (unsigned short*)(smem + 65536);       // 2 halves x 8 KB
    unsigned short* Ps1 = (unsigned short*)(smem + 81920);
    float* E2s  = (float*)(smem + 98304);
    float* G2s  = (float*)(smem + 106496);
    float* Srow = (float*)(smem + 114688);
    float* Sred = (float*)(smem + 114944);
    float* T    = (float*)smem;                 // 33.8 KB alias after final barrier

    const int tid  = threadIdx.x;
    const int gblk = blockIdx.x;
    const int b    = gblk & 7;                  // XCD-locality
    const int i0   = (gblk >> 3) * 64;

    #pragma unroll
    for (int k = 0; k < NN / 512; ++k) {
        E2s[tid + 512 * k] = E2g[b * NN + tid + 512 * k];
        G2s[tid + 512 * k] = G2g[b * NN + tid + 512 * k];
    }

    // P role: row = tid>>3 (64 rows), 8 j-elems per half at pjb*8
    const int prow = tid >> 3;
    const int pjb  = tid & 7;
    const float f1r = f1[b * NN + i0 + prow];
    const float E1r = __expf(f1r);
    const float G1r = __expf(0.2f * f1r);
    const int psw = ((pjb ^ (prow & 7)) << 3);
    const unsigned int* padjRow = padj + (size_t)(i0 + prow) * 64;

    // MFMA role: wave (wr,wc) in 2x4
    const int w    = tid >> 6;
    const int wr   = w >> 2, wc = w & 3;
    const int lane = tid & 63;
    const int fr   = lane & 15;
    const int fk   = lane >> 4;
    f32x4 acc00 = {0.f,0.f,0.f,0.f}, acc01 = {0.f,0.f,0.f,0.f};
    f32x4 acc10 = {0.f,0.f,0.f,0.f}, acc11 = {0.f,0.f,0.f,0.f};
    float s_part = 0.f;

    // B staging per 64-j sub-tile: 1024 x 16B slots, 2 per thread (proven swizzle)
    const size_t wbase = (size_t)b * 128 * NN;
    const int g0 = tid,       gd0 = g0 >> 3, gj0 = (g0 & 7) * 8;
    const int g1 = tid + 512, gd1 = g1 >> 3, gj1 = (g1 & 7) * 8;
    const int sw0 = gd0 * 64 + ((((g0) & 7) ^ (gd0 & 7)) << 3);
    const int sw1 = gd1 * 64 + ((((g1) & 7) ^ (gd1 & 7)) << 3);

    uint4 brA0, brA1, brA2, brA3, brB0, brB1, brB2, brB3;
    unsigned int pwA0, pwA1, pwB0, pwB1;

#define LOADSET(s, c) do {  /* c = fat-chunk index; sub-chunks 2c, 2c+1 */    \
        br##s##0 = *(const uint4*)&WhbT[wbase + (size_t)gd0 * NN + (2*(c)) * 64 + gj0]; \
        br##s##1 = *(const uint4*)&WhbT[wbase + (size_t)gd1 * NN + (2*(c)) * 64 + gj1]; \
        br##s##2 = *(const uint4*)&WhbT[wbase + (size_t)gd0 * NN + (2*(c)+1) * 64 + gj0]; \
        br##s##3 = *(const uint4*)&WhbT[wbase + (size_t)gd1 * NN + (2*(c)+1) * 64 + gj1]; \
        pw##s##0 = padjRow[(2*(c)) * 2 + (pjb >> 2)];                        \
        pw##s##1 = padjRow[(2*(c)+1) * 2 + (pjb >> 2)];                      \
    } while (0)

#define PHALF(Bsb, Psb, pwv, brX, brY, sc, h) do {                           \
        float4 eA = *(const float4*)&E2s[(sc) * 64 + pjb * 8];               \
        float4 eB = *(const float4*)&E2s[(sc) * 64 + pjb * 8 + 4];           \
        float4 gA = *(const float4*)&G2s[(sc) * 64 + pjb * 8];               \
        float4 gB = *(const float4*)&G2s[(sc) * 64 + pjb * 8 + 4];           \
        float ev[8], gv[8];                                                  \
        *(float4*)&ev[0] = eA; *(float4*)&ev[4] = eB;                        \
        *(float4*)&gv[0] = gA; *(float4*)&gv[4] = gB;                        \
        unsigned int pbits = ((pwv) >> ((pjb & 3) << 3)) & 0xffu;            \
        unsigned short pks[8];                                               \
        float ssum = 0.f;                                                    \
        _Pragma("unroll")                                                    \
        for (int e = 0; e < 8; ++e) {                                        \
            float mv = E1r * ev[e];                                          \
            float gg = G1r * gv[e];                                          \
            float wv = fmaxf(mv, gg);                                        \
            wv = ((pbits >> e) & 1u) ? wv : 0.f;                             \
            unsigned short bw = f2bf(wv);                                    \
            pks[e] = bw;                                                     \
            ssum += bf2f(bw);                                                \
        }                                                                    \
        s_part += ssum;                                                      \
        *(uint4*)&(Bsb)[(h) * 8192 + sw0] = brX;                             \
        *(uint4*)&(Bsb)[(h) * 8192 + sw1] = brY;                             \
        uint4 pv;                                                            \
        pv.x = (unsigned int)pks[0] | ((unsigned int)pks[1] << 16);          \
        pv.y = (unsigned int)pks[2] | ((unsigned int)pks[3] << 16);          \
        pv.z = (unsigned int)pks[4] | ((unsigned int)pks[5] << 16);          \
        pv.w = (unsigned int)pks[6] | ((unsigned int)pks[7] << 16);          \
        *(uint4*)&(Psb)[(h) * 4096 + prow * 64 + psw] = pv;                  \
    } while (0)

#define PSTAGE(Bsb, Psb, s, c) do {                                          \
        PHALF(Bsb, Psb, pw##s##0, br##s##0, br##s##1, 2*(c),     0);         \
        PHALF(Bsb, Psb, pw##s##1, br##s##2, br##s##3, 2*(c) + 1, 1);         \
    } while (0)

#define MHALF(Bsb, Psb, h) do {                                              \
        _Pragma("unroll")                                                    \
        for (int ks = 0; ks < 2; ++ks) {                                     \
            const int jbl = ks * 4 + fk;                                     \
            const int sb  = ((jbl ^ (fr & 7)) << 3);                         \
            short8 aF0 = *(const short8*)&(Psb)[(h) * 4096 + (wr * 32 + fr) * 64 + sb]; \
            short8 aF1 = *(const short8*)&(Psb)[(h) * 4096 + (wr * 32 + 16 + fr) * 64 + sb]; \
            short8 bF0 = *(const short8*)&(Bsb)[(h) * 8192 + (wc * 32 + fr) * 64 + sb]; \
            short8 bF1 = *(const short8*)&(Bsb)[(h) * 8192 + (wc * 32 + 16 + fr) * 64 + sb]; \
            acc00 = __builtin_amdgcn_mfma_f32_16x16x32_bf16(aF0, bF0, acc00, 0, 0, 0); \
            acc01 = __builtin_amdgcn_mfma_f32_16x16x32_bf16(aF0, bF1, acc01, 0, 0, 0); \
            acc10 = __builtin_amdgcn_mfma_f32_16x16x32_bf16(aF1, bF0, acc10, 0, 0, 0); \
            acc11 = __builtin_amdgcn_mfma_f32_16x16x32_bf16(aF1, bF1, acc11, 0, 0, 0); \
        }                                                                    \
    } while (0)

#define MFMAC(Bsb, Psb) do {                                                 \
        __builtin_amdgcn_s_setprio(1);                                       \
        MHALF(Bsb, Psb, 0);                                                  \
        MHALF(Bsb, Psb, 1);                                                  \
        __builtin_amdgcn_s_setprio(0);                                       \
    } while (0)

    // prologue: fat chunk 0 -> buf0; prefetch fat chunk 1
    LOADSET(A, 0);
    __syncthreads();                 // E2s/G2s ready (PHALF reads them)
    PSTAGE(Bs0, Ps0, A, 0);
    LOADSET(B, 1);
    __syncthreads();                 // buf0 ready

    #pragma unroll 1
    for (int cc = 0; cc < NF; cc += 2) {
        PSTAGE(Bs1, Ps1, B, cc + 1);
        if (cc + 2 < NF) LOADSET(A, cc + 2);
        MFMAC(Bs0, Ps0);
        __syncthreads();
        if (cc + 2 < NF) PSTAGE(Bs0, Ps0, A, cc + 2);
        if (cc + 3 < NF) LOADSET(B, cc + 3);
        MFMAC(Bs1, Ps1);
        __syncthreads();
    }

#undef LOADSET
#undef PHALF
#undef PSTAGE
#undef MHALF
#undef MFMAC

    // row-sum: 8 threads per row
    {
        float v = s_part;
        v += __shfl_xor(v, 1); v += __shfl_xor(v, 2); v += __shfl_xor(v, 4);
        if (pjb == 0) Srow[prow] = v;
    }
    __syncthreads();
    if (tid < 64) Sred[tid] = 1.0f / Srow[tid];
    __syncthreads();

    // normalize + elu into T (aliases tile buffers; all MFMA reads done)
    #pragma unroll
    for (int it = 0; it < 2; ++it) {
        #pragma unroll
        for (int dt = 0; dt < 2; ++dt) {
            f32x4 av = (it == 0) ? (dt == 0 ? acc00 : acc01)
                                 : (dt == 0 ? acc10 : acc11);
            #pragma unroll
            for (int r = 0; r < 4; ++r) {
                const int i = wr * 32 + it * 16 + fk * 4 + r;
                const int d = wc * 32 + dt * 16 + fr;
                float hv = av[r] * Sred[i];
                hv = (hv > 0.f) ? hv : expm1f(hv);
                T[i * 132 + d] = hv;
            }
        }
    }
    __syncthreads();

    #pragma unroll
    for (int k = 0; k < 4; ++k) {
        const int g   = tid + 512 * k;     // 2048 float4 = 64 x 128
        const int row = g >> 5;
        const int d4  = (g & 31) * 4;
        float4 h = *(const float4*)&T[row * 132 + d4];
        *(float4*)&out[((size_t)(b * NN) + i0 + row) * DD + d4] = h;
    }
}

extern "C" void kernel_launch(void* const* d_in, const int* in_sizes, int n_in,
                              void* d_out, int out_size, void* d_ws, size_t ws_size,
                              hipStream_t stream) {
    const float* x   = (const float*)d_in[0];
    const int*   adj = (const int*)d_in[1];
    const float* W   = (const float*)d_in[2];
    const float* a   = (const float*)d_in[3];
    float* out = (float*)d_out;

    char* p = (char*)d_ws;
    unsigned short* WhbT = (unsigned short*)p; p += (size_t)BB * NN * DD * 2;  // 4 MB
    float* f1  = (float*)p; p += (size_t)BB * NN * 4;                          // 64 KB
    float* E2g = (float*)p; p += (size_t)BB * NN * 4;                          // 64 KB
    float* G2g = (float*)p; p += (size_t)BB * NN * 4;                          // 64 KB
    unsigned int* padj = (unsigned int*)p;    p += (size_t)NN * 64 * 4;        // 512 KB

    prep_wh_kernel<<<PACKB + (NN / 64) * BB, 256, 0, stream>>>(
        adj, padj, x, W, a, WhbT, f1, E2g, G2g);
    gat_kernel<<<(NN / 64) * BB, 512, 0, stream>>>(
        WhbT, padj, f1, E2g, G2g, out);
}